// Round 17
// baseline (318.656 us; speedup 1.0000x reference)
//
#include <hip/hip_runtime.h>
#include <hip/hip_fp8.h>
#include <math.h>

typedef float f32x4 __attribute__((ext_vector_type(4)));
typedef unsigned short u16;
typedef unsigned char u8;

typedef const __attribute__((address_space(1))) unsigned int ga_u32;
typedef __attribute__((address_space(3))) unsigned int ls_u32;

__device__ __forceinline__ void gl16(const void* g, void* l) {
    __builtin_amdgcn_global_load_lds((ga_u32*)g, (ls_u32*)l, 16, 0, 0);
}

__device__ __forceinline__ u16 f2bf(float f) {
    union { float f; unsigned u; } v; v.f = f;
    return (u16)((v.u + 0x7FFFu + ((v.u >> 16) & 1u)) >> 16);
}
__device__ __forceinline__ float bf2f(u16 h) {
    union { unsigned u; float f; } v; v.u = ((unsigned)h) << 16;
    return v.f;
}
// OCP e4m3fn quantize (RNE, saturating)
__device__ __forceinline__ u8 f2q(float f) {
    __hip_fp8_e4m3 t(f);
    return (u8)t.__x;
}
__device__ __forceinline__ long ld8(const u8* p) { return *(const long*)p; }

__device__ __forceinline__ float splusf(float x) {
    return fmaxf(x, 0.f) + __logf(1.f + __expf(-fabsf(x)));
}
// inverse of the channel permutation rho (sorts channels by (c%63, c)).
__device__ __forceinline__ int invperm(int k) {
    int m, q;
    if (k < 20) { m = k / 5; q = k - 5 * m; }
    else        { m = (k - 4) >> 2; q = (k - 4) & 3; }
    return m + 63 * q;
}

#define MID_ACT_P 272
#define WSCALE 64.f
#define WINV (1.f / 64.f)

// ---------------------------------------------------------------------------
// setup: masked fp8 weights (value x64) in per-wave fragment layouts, hidden
// space relabeled by rho (R15). W1/WB: [l][w][frag][lane][8].
// WO: [l][y32][ks8][frag6][lane][8] (K-prefix banded after permutation).
// ---------------------------------------------------------------------------
__global__ __launch_bounds__(256) void setup_w(
    const float* __restrict__ Win, const float* __restrict__ bin,
    const float* __restrict__ Wctx, const float* __restrict__ bctx,
    const float* __restrict__ Wblk, const float* __restrict__ Wout,
    const float* __restrict__ bout, const float* __restrict__ eta,
    u8* __restrict__ W1, float* __restrict__ B1, u8* __restrict__ WB,
    u8* __restrict__ WO, float* __restrict__ BO, u8* __restrict__ AXE)
{
    const long N1 = 8L * 8 * 8 * 64 * 8;         // W1
    const long N2 = 8L * 256;
    const long N3 = 8L * 4 * 8 * 16 * 64 * 8;    // WB
    const long N4 = 8L * 32 * 8 * 6 * 64 * 8;    // WO
    const long N5 = 8L * 3072;
    const long N6 = 8192L * 32;
    const long tot = N1 + N2 + N3 + N4 + N5 + N6;
    for (long i = (long)blockIdx.x * blockDim.x + threadIdx.x; i < tot;
         i += (long)gridDim.x * blockDim.x) {
        long t = i;
        if (t < N1) {
            int off = (int)(t & 7), lane = (int)((t >> 3) & 63);
            int frag = (int)((t >> 9) & 7), wv = (int)((t >> 12) & 7);
            long l = t >> 15;
            int ks = frag >> 1, f = frag & 1;
            int prow = wv * 32 + f * 16 + (lane & 15);
            int row = invperm(prow);
            int c = ks * 32 + ((lane >> 4) << 3) + off;
            float v = 0.f;
            if (c < 64)      v = Win[(l * 256 + row) * 64 + c] * (((row % 63) >= c) ? 1.f : 0.f);
            else if (c < 96) v = Wctx[(l * 256 + row) * 32 + (c - 64)];
            W1[t] = f2q(v * WSCALE);
        } else if ((t -= N1) < N2) {
            long l = t >> 8; int k = (int)(t & 255);
            int c = invperm(k);
            B1[t] = bin[l * 256 + c] + bctx[l * 256 + c];
        } else if ((t -= N2) < N3) {
            int off = (int)(t & 7), lane = (int)((t >> 3) & 63);
            int frag = (int)((t >> 9) & 15), wv = (int)((t >> 13) & 7);
            int bi = (int)((t >> 16) & 3);
            long l = t >> 18;
            int prow = wv * 32 + (frag & 1) * 16 + (lane & 15);
            int pc   = ((frag >> 1) << 5) + ((lane >> 4) << 3) + off;
            int row = invperm(prow), c = invperm(pc);
            float v = Wblk[(((size_t)l * 4 + bi) * 256 + row) * 256 + c] *
                      (((row % 63) >= (c % 63)) ? 1.f : 0.f);
            WB[t] = f2q(v * WSCALE);
        } else if ((t -= N3) < N4) {
            long l = t / 786432; int rem = (int)(t % 786432);
            int y = rem / 24576, r2 = rem % 24576;
            int ks = r2 / 3072, r3 = r2 % 3072;
            int frag = r3 / 512, r4 = r3 % 512;
            int lane = r4 / 8, off = r4 % 8;
            int op = y * 96 + frag * 16 + (lane & 15);
            int pj = ks * 32 + ((lane >> 4) << 3) + off;
            int j = invperm(pj);
            int fd = op / 48, mm = op % 48;
            float v = 0.f;
            if (mm < 47 && fd > (j % 63))
                v = Wout[((size_t)l * 3008 + fd * 47 + mm) * 256 + j];
            WO[t] = f2q(v * WSCALE);
        } else if ((t -= N4) < N5) {
            long l = t / 3072; int op = (int)(t % 3072);
            int fd = op / 48, mm = op % 48;
            BO[t] = (mm < 47) ? bout[l * 3008 + (long)fd * 47 + mm] : 0.f;
        } else {
            t -= N5;
            long b = t / 32; int p = (int)(t % 32);
            AXE[b * 96 + 64 + p] = f2q(eta[t]);
        }
    }
}

// permuted copy of bblk
__global__ __launch_bounds__(256) void perm_bias(
    const float* __restrict__ bblk, float* __restrict__ BBp)
{
    int t = blockIdx.x * 256 + threadIdx.x;   // 8*4*256 = 8192
    int k = t & 255;
    BBp[t] = bblk[(t & ~255) | invperm(k)];
}

// ---------------------------------------------------------------------------
// data stats
// ---------------------------------------------------------------------------
__global__ __launch_bounds__(128) void dstat(const float* __restrict__ D,
                                             float* __restrict__ DM)
{
    int j = threadIdx.x;
    float s = 0.f, q = 0.f;
    if (j < 65) {
        for (int m = 0; m < 256; ++m) {
            float v = D[m * 65 + j];
            s += v; q += v * v;
        }
        DM[j] = s * (1.f / 256.f);
    }
    __shared__ float red[128];
    red[j] = q; __syncthreads();
    for (int st = 64; st > 0; st >>= 1) {
        if (j < st) red[j] += red[j + st];
        __syncthreads();
    }
    if (j == 0) DM[65] = red[0] * (1.f / 256.f);
}

// ---------------------------------------------------------------------------
// prep0: flip z -> XF (f32) + AXE cols 0..63 (fp8)
// ---------------------------------------------------------------------------
__global__ __launch_bounds__(256) void prep0(
    const float* __restrict__ z, float* __restrict__ XF, u8* __restrict__ AXE)
{
    size_t gt = (size_t)blockIdx.x * 256 + threadIdx.x;
    size_t b = gt >> 6; int f = (int)(gt & 63);
    float v = z[b * 64 + (63 - f)];
    XF[gt] = v;
    AXE[b * 96 + f] = f2q(v);
}

// ---------------------------------------------------------------------------
// mid helpers: coalesced frag loads / MFMA consume (fp8)
// ---------------------------------------------------------------------------
template<int NF>
__device__ __forceinline__ void loadW(const u8* __restrict__ gW, int lane,
                                      long (&wf)[NF])
{
#pragma unroll
    for (int j = 0; j < NF; ++j)
        wf[j] = ld8(gW + (j * 64 + lane) * 8);
}
template<int NF>
__device__ __forceinline__ void mfmaW(const long (&wf)[NF],
                                      const u8* __restrict__ act,
                                      int fr, int kg, f32x4 (&T)[2])
{
#pragma unroll
    for (int ks = 0; ks < NF / 2; ++ks) {
        long af = ld8(&act[fr * MID_ACT_P + ks * 32 + kg * 8]);
        T[0] = __builtin_amdgcn_mfma_f32_16x16x32_fp8_fp8(wf[ks * 2 + 0], af, T[0], 0, 0, 0);
        T[1] = __builtin_amdgcn_mfma_f32_16x16x32_fp8_fp8(wf[ks * 2 + 1], af, T[1], 0, 0, 0);
    }
}

// fused_mid: all 5 mid GEMMs, fp8, SOFTWARE-PIPELINED weight stream:
// stage s+1's loads are issued right after stage s's MFMAs consume their
// fragments, so the ~400cyc L2 latency hides under {bar, epilogue, bar}.
// Peak VGPR unchanged (cur fragment buffer is dead when next is issued).
__global__ __launch_bounds__(512) void fused_mid(
    const u8* __restrict__ AXE, const u8* __restrict__ W1l,
    const float* __restrict__ B1l, const u8* __restrict__ WBl,
    const float* __restrict__ bbl, u8* __restrict__ HB)
{
    __shared__ u8 act[16 * MID_ACT_P];   // 4352 B
    const int tid = threadIdx.x;
    const int lane = tid & 63;
    const int wv = tid >> 6;
    const int fr = lane & 15, kg = lane >> 4;
    const int b0 = blockIdx.x * 16;
    const int ch0 = wv * 32;

    // stage-0 activations: AXE rows b0..b0+15 (96 u8 each = 6 int4)
    if (tid < 96) {
        int row = tid / 6, part = tid - row * 6;
        *(int4*)&act[row * MID_ACT_P + part * 16] =
            *(const int4*)&AXE[(size_t)(b0 + row) * 96 + part * 16];
    }

    f32x4 H[2], T[2];

    auto zeroT = [&]() {
        T[0] = (f32x4){0.f, 0.f, 0.f, 0.f};
        T[1] = (f32x4){0.f, 0.f, 0.f, 0.f};
    };
    // mode 0: H=T/64+b, act=relu(H); 1: act=relu(T/64+b); 2: H+=..., act;
    // mode 3: H+=T/64+b, HB=fp8(H)
    auto epi = [&](const float* bias, int mode) {
#pragma unroll
        for (int m = 0; m < 2; ++m) {
            const int cb = ch0 + m * 16 + kg * 4;
            const float4 bs = *(const float4*)&bias[cb];
            f32x4 v = T[m];
            v[0] = v[0] * WINV + bs.x; v[1] = v[1] * WINV + bs.y;
            v[2] = v[2] * WINV + bs.z; v[3] = v[3] * WINV + bs.w;
            if (mode == 0) H[m] = v;
            if (mode == 2 || mode == 3) {
                H[m][0] += v[0]; H[m][1] += v[1];
                H[m][2] += v[2]; H[m][3] += v[3];
                v = H[m];
            }
            unsigned pk;
            if (mode != 3) {
                pk = (unsigned)f2q(fmaxf(v[0], 0.f))
                   | ((unsigned)f2q(fmaxf(v[1], 0.f)) << 8)
                   | ((unsigned)f2q(fmaxf(v[2], 0.f)) << 16)
                   | ((unsigned)f2q(fmaxf(v[3], 0.f)) << 24);
                *(unsigned*)&act[fr * MID_ACT_P + cb] = pk;
            } else {
                pk = (unsigned)f2q(v[0]) | ((unsigned)f2q(v[1]) << 8)
                   | ((unsigned)f2q(v[2]) << 16) | ((unsigned)f2q(v[3]) << 24);
                const int b = b0 + fr;
                const size_t idx =
                    (((((size_t)(b >> 7) * 8 + (cb >> 5)) * 8 + ((b >> 4) & 7)) * 64)
                     + (((cb >> 3) & 3) * 16 + (b & 15))) * 8 + (cb & 7);
                *(unsigned*)&HB[idx] = pk;
            }
        }
    };

    // ---- pipelined stage chain ----
    long wfa[6];  loadW<6>(W1l + wv * 4096, lane, wfa);     // overlaps act stage
    zeroT();
    __syncthreads();                                         // act0 visible
    mfmaW<6>(wfa, act, fr, kg, T);
    long wfb[16]; loadW<16>(WBl + 0 * 65536 + wv * 8192, lane, wfb);
    __syncthreads();
    epi(B1l, 0);
    zeroT();
    __syncthreads();
    mfmaW<16>(wfb, act, fr, kg, T);
    long wfc[16]; loadW<16>(WBl + 1 * 65536 + wv * 8192, lane, wfc);
    __syncthreads();
    epi(bbl, 1);
    zeroT();
    __syncthreads();
    mfmaW<16>(wfc, act, fr, kg, T);
    long wfd[16]; loadW<16>(WBl + 2 * 65536 + wv * 8192, lane, wfd);
    __syncthreads();
    epi(bbl + 256, 2);
    zeroT();
    __syncthreads();
    mfmaW<16>(wfd, act, fr, kg, T);
    long wfe[16]; loadW<16>(WBl + 3 * 65536 + wv * 8192, lane, wfe);
    __syncthreads();
    epi(bbl + 2 * 256, 1);
    zeroT();
    __syncthreads();
    mfmaW<16>(wfe, act, fr, kg, T);
    __syncthreads();
    epi(bbl + 3 * 256, 3);
}

// ---------------------------------------------------------------------------
// Out-GEMM (128x96 tile, fp8) + fused RQS spline. K-banded (nk=(by+4)>>2),
// long blocks scheduled first (by = 31 - blockIdx.y). gl16 frag staging, dbuf.
// (R16-proven, unchanged.)
// ---------------------------------------------------------------------------
__global__ __launch_bounds__(256) void gemm_out_spline(
    const u8* __restrict__ A, const u8* __restrict__ Wo,
    const float* __restrict__ bo, const float* __restrict__ XF,
    float* __restrict__ Xn, float* __restrict__ XFnext, u8* __restrict__ AXE,
    float* __restrict__ LDP, int first)
{
    __shared__ u16 SM16[13312];          // 26624 B; staging aliases first 14336
    u8* SM8 = (u8*)SM16;
    const int tid = threadIdx.x;
    const int lane = tid & 63, wv = tid >> 6;
    const int wm = wv >> 1, wn = wv & 1;
    const int fr = lane & 15, kg = lane >> 4;
    const int by = 31 - (int)blockIdx.y;       // long blocks first
    const int m0 = blockIdx.x * 128, n0 = by * 96;
    const int nk = (by + 4) >> 2;              // 1..8 K-slices

    u8* Ab = SM8;                    // 2 x 4096 u8
    u8* Bb = SM8 + 8192;             // 2 x 3072 u8

    const u8* gA = A  + (size_t)blockIdx.x * 16384;   // [ks8][frag8][lane][8]
    const u8* gB = Wo + (size_t)by * 24576;           // [ks8][frag6][lane][8]

    f32x4 acc[4][3];
#pragma unroll
    for (int m = 0; m < 4; ++m)
#pragma unroll
        for (int n = 0; n < 3; ++n) acc[m][n] = (f32x4){0.f, 0.f, 0.f, 0.f};

    // prologue: slice 0 -> buf0 (linear gl16 copies)
    gl16(gA + tid * 16, Ab + tid * 16);
    if (tid < 192) gl16(gB + tid * 16, Bb + tid * 16);

    for (int ks = 0; ks < nk; ++ks) {
        __syncthreads();   // drains buf[ks&1] gl16; orders buffer reuse
        if (ks + 1 < nk) {
            const u8* sa = gA + (ks + 1) * 4096;
            const u8* sb = gB + (ks + 1) * 3072;
            u8* na = Ab + ((ks + 1) & 1) * 4096;
            u8* nb = Bb + ((ks + 1) & 1) * 3072;
            gl16(sa + tid * 16, na + tid * 16);
            if (tid < 192) gl16(sb + tid * 16, nb + tid * 16);
        }
        const u8* cA = Ab + (ks & 1) * 4096;
        const u8* cB = Bb + (ks & 1) * 3072;
        long af[4], bf[3];
#pragma unroll
        for (int m = 0; m < 4; ++m)
            af[m] = ld8(&cA[(wm * 4 + m) * 512 + lane * 8]);
#pragma unroll
        for (int n = 0; n < 3; ++n)
            bf[n] = ld8(&cB[(wn * 3 + n) * 512 + lane * 8]);
#pragma unroll
        for (int m = 0; m < 4; ++m)
#pragma unroll
            for (int n = 0; n < 3; ++n)
                acc[m][n] = __builtin_amdgcn_mfma_f32_16x16x32_fp8_fp8(bf[n], af[m], acc[m][n], 0, 0, 0);
    }
    __syncthreads();   // all frag reads done before dump aliases the buffers

    // dump acc/64 (+bias) as bf16, pitch 104 u16
#pragma unroll
    for (int m = 0; m < 4; ++m) {
        const int row = wm * 64 + m * 16 + fr;
#pragma unroll
        for (int n = 0; n < 3; ++n) {
            const int c0 = wn * 48 + n * 16 + kg * 4;
            const float4 bs = *(const float4*)&bo[n0 + c0];
            short4 q;
            q.x = (short)f2bf(acc[m][n][0] * WINV + bs.x);
            q.y = (short)f2bf(acc[m][n][1] * WINV + bs.y);
            q.z = (short)f2bf(acc[m][n][2] * WINV + bs.z);
            q.w = (short)f2bf(acc[m][n][3] * WINV + bs.w);
            *(short4*)&SM16[row * 104 + c0] = q;
        }
    }
    __syncthreads();

    // ---- RQS spline: one thread per (row, feature); 256 = 128 x 2 ----
    typedef short bf16x8 __attribute__((ext_vector_type(8)));
    const int r = tid >> 1, fi = tid & 1;
    const int b = m0 + r;
    const int fg = by * 2 + fi;
    const u16* o_ = &SM16[r * 104 + fi * 48];
    bf16x8 v0 = *(const bf16x8*)(o_);
    bf16x8 v1 = *(const bf16x8*)(o_ + 8);
    bf16x8 v2 = *(const bf16x8*)(o_ + 16);
    bf16x8 v3 = *(const bf16x8*)(o_ + 24);
    bf16x8 v4 = *(const bf16x8*)(o_ + 32);
    bf16x8 v5 = *(const bf16x8*)(o_ + 40);

    float xin = XF[(size_t)b * 64 + fg];
    bool inside = (xin >= -10.f) && (xin <= 10.f);
    float xs = fminf(fmaxf(xin, -10.f), 10.f);

    float ew[16], eh[16], ud[15];
#pragma unroll
    for (int i = 0; i < 8; ++i) {
        ew[i]     = bf2f((u16)v0[i]) * 0.0625f;
        ew[8 + i] = bf2f((u16)v1[i]) * 0.0625f;
        eh[i]     = bf2f((u16)v2[i]) * 0.0625f;
        eh[8 + i] = bf2f((u16)v3[i]) * 0.0625f;
    }
#pragma unroll
    for (int i = 0; i < 8; ++i) ud[i] = bf2f((u16)v4[i]);
#pragma unroll
    for (int i = 0; i < 7; ++i) ud[8 + i] = bf2f((u16)v5[i]);

    float mw = ew[0], mh = eh[0];
#pragma unroll
    for (int i = 1; i < 16; ++i) { mw = fmaxf(mw, ew[i]); mh = fmaxf(mh, eh[i]); }
    float sw = 0.f, sh = 0.f;
#pragma unroll
    for (int i = 0; i < 16; ++i) {
        ew[i] = __expf(ew[i] - mw); sw += ew[i];
        eh[i] = __expf(eh[i] - mh); sh += eh[i];
    }
    const float kw = 20.f * (1.f - 1.6e-7f) / sw;
    const float kh = 20.f * (1.f - 1.6e-7f) / sh;

    float cwk = -10.f, chk = -10.f;
    float icw = -10.f, ich = -10.f, iw = 1.f, ih = 1.f, udl = 0.f, udr = 0.f;
    int selk = 0;
#pragma unroll
    for (int k = 0; k < 16; ++k) {
        const float cw1 = (k == 15) ? 10.f : cwk + (2e-7f + kw * ew[k]);
        const float ch1 = (k == 15) ? 10.f : chk + (2e-7f + kh * eh[k]);
        if (xs >= cwk) {
            selk = k;
            icw = cwk; iw = cw1 - cwk;
            ich = chk; ih = ch1 - chk;
            udl = (k >= 1)  ? ud[k - 1] : 0.f;
            udr = (k <= 14) ? ud[k]     : 0.f;
        }
        cwk = cw1; chk = ch1;
    }
    float d0 = (selk == 0)  ? 1.f : 1e-8f + splusf(udl);
    float d1 = (selk == 15) ? 1.f : 1e-8f + splusf(udr);
    float delta = ih / iw;
    float t = (xs - icw) / iw;
    float tt = t * (1.f - t);
    float denom = delta + (d0 + d1 - 2.f * delta) * tt;
    float y = ich + ih * (delta * t * t + d0 * tt) / denom;
    float omt = 1.f - t;
    float dnum = delta * delta * (d1 * t * t + 2.f * delta * tt + d0 * omt * omt);
    float ldv = __logf(dnum) - 2.f * __logf(denom);
    if (!inside) { y = xin; ldv = 0.f; }

    Xn[(size_t)b * 64 + fg] = y;
    XFnext[(size_t)b * 64 + (63 - fg)] = y;
    AXE[(size_t)b * 96 + (63 - fg)] = f2q(y);

    float other = __shfl_xor(ldv, 1);
    if (fi == 0) {
        size_t o = (size_t)b * 32 + by;
        float v = ldv + other;
        LDP[o] = first ? v : (LDP[o] + v);
    }
}

// ---------------------------------------------------------------------------
// finals: stick-breaking + per-sample objective, then reduction
// ---------------------------------------------------------------------------
__global__ __launch_bounds__(256) void final1(
    const float* __restrict__ X, const float* __restrict__ z,
    const float* __restrict__ LDP, const float* __restrict__ DM,
    float* __restrict__ PART)
{
    int tid = threadIdx.x;
    int b = blockIdx.x * 256 + tid;
    float ldt = 0.f;
    for (int g = 0; g < 32; ++g) ldt += LDP[(size_t)b * 32 + g];
    float pre = 0.f, lvs = 0.f, wls = 0.f, lp = 0.f, tdm = 0.f, tsq = 0.f;
    const float LCLIP = -23.02585093f;
    for (int i = 0; i < 64; ++i) {
        float xi = X[(size_t)b * 64 + i];
        float lv = -splusf(-xi), l1 = -splusf(xi);
        float lt = lv + pre;
        float th = __expf(lt);
        lp += fmaxf(lt, LCLIP);
        tdm += th * DM[i]; tsq += th * th;
        lvs += lv; wls += (float)(64 - i) * l1;
        pre += l1;
    }
    float th = __expf(pre);
    lp += fmaxf(pre, LCLIP); tdm += th * DM[64]; tsq += th * th;
    float zs = 0.f;
    for (int i = 0; i < 64; ++i) { float zz = z[(size_t)b * 64 + i]; zs += zz * zz; }
    float logqz = -0.5f * zs - 58.812066f;
    float log_q = logqz - (ldt + lvs + wls);
    float log_lik = -0.5f * (DM[65] - 2.f * tdm + tsq);
    float val = log_q - lp - log_lik;

    __shared__ float red[256];
    red[tid] = val; __syncthreads();
    for (int s = 128; s > 0; s >>= 1) {
        if (tid < s) red[tid] += red[tid + s];
        __syncthreads();
    }
    if (tid == 0) PART[blockIdx.x] = red[0];
}

__global__ __launch_bounds__(64) void final2(const float* __restrict__ PART,
                                             float* __restrict__ out)
{
    int tid = threadIdx.x;
    float s = (tid < 32) ? PART[tid] : 0.f;
    for (int o = 16; o > 0; o >>= 1) s += __shfl_down(s, o);
    if (tid == 0) out[0] = s * (1.f / 8192.f);
}

// ---------------------------------------------------------------------------
extern "C" void kernel_launch(void* const* d_in, const int* in_sizes, int n_in,
                              void* d_out, int out_size, void* d_ws, size_t ws_size,
                              hipStream_t stream)
{
    (void)in_sizes; (void)n_in; (void)out_size; (void)ws_size;
    const float* z    = (const float*)d_in[0];
    const float* eta  = (const float*)d_in[1];
    const float* dat  = (const float*)d_in[2];
    const float* Win  = (const float*)d_in[3];
    const float* bin  = (const float*)d_in[4];
    const float* Wctx = (const float*)d_in[5];
    const float* bctx = (const float*)d_in[6];
    const float* Wblk = (const float*)d_in[7];
    const float* bblk = (const float*)d_in[8];
    const float* Wout = (const float*)d_in[9];
    const float* bout = (const float*)d_in[10];
    float* out = (float*)d_out;

    char* w = (char*)d_ws;
    size_t off = 0;
    auto alloc = [&](size_t bytes) {
        void* p = w + off;
        off += (bytes + 255) & ~(size_t)255;
        return p;
    };
    u8*    W1  = (u8*)   alloc(8L * 32768);
    float* B1  = (float*)alloc(8L * 256 * 4);
    u8*    WB  = (u8*)   alloc(8L * 262144);
    float* BBp = (float*)alloc(8L * 4 * 256 * 4);
    u8*    WO  = (u8*)   alloc(8L * 786432);
    float* BO  = (float*)alloc(8L * 3072 * 4);
    u8*    AXE = (u8*)   alloc(8192L * 96);
    float* XFa = (float*)alloc(8192L * 64 * 4);
    float* XFb = (float*)alloc(8192L * 64 * 4);
    float* XC  = (float*)alloc(8192L * 64 * 4);
    u8*    HB  = (u8*)   alloc(8192L * 256);
    float* LDP = (float*)alloc(8192L * 32 * 4);
    float* DM  = (float*)alloc(66 * 4);
    float* PART= (float*)alloc(64 * 4);

    setup_w<<<dim3(2048), dim3(256), 0, stream>>>(
        Win, bin, Wctx, bctx, Wblk, Wout, bout, eta,
        W1, B1, WB, WO, BO, AXE);
    perm_bias<<<dim3(32), dim3(256), 0, stream>>>(bblk, BBp);
    dstat<<<dim3(1), dim3(128), 0, stream>>>(dat, DM);
    prep0<<<dim3(2048), dim3(256), 0, stream>>>(z, XFa, AXE);

    for (int l = 0; l < 8; ++l) {
        float* XFin  = (l & 1) ? XFb : XFa;
        float* XFout = (l & 1) ? XFa : XFb;
        fused_mid<<<dim3(512), dim3(512), 0, stream>>>(
            AXE, W1 + (size_t)l * 32768, B1 + l * 256,
            WB + (size_t)l * 262144, BBp + (size_t)l * 4 * 256, HB);
        gemm_out_spline<<<dim3(64, 32), dim3(256), 0, stream>>>(
            HB, WO + (size_t)l * 786432, BO + l * 3072, XFin,
            XC, XFout, AXE, LDP, (l == 0) ? 1 : 0);
    }
    final1<<<dim3(32), dim3(256), 0, stream>>>(XC, z, LDP, DM, PART);
    final2<<<dim3(1), dim3(64), 0, stream>>>(PART, out);
}

// Round 18
// 286.082 us; speedup vs baseline: 1.1139x; 1.1139x over previous
//
#include <hip/hip_runtime.h>
#include <hip/hip_fp8.h>
#include <math.h>

typedef float f32x4 __attribute__((ext_vector_type(4)));
typedef unsigned short u16;
typedef unsigned char u8;

typedef const __attribute__((address_space(1))) unsigned int ga_u32;
typedef __attribute__((address_space(3))) unsigned int ls_u32;

__device__ __forceinline__ void gl16(const void* g, void* l) {
    __builtin_amdgcn_global_load_lds((ga_u32*)g, (ls_u32*)l, 16, 0, 0);
}

__device__ __forceinline__ u16 f2bf(float f) {
    union { float f; unsigned u; } v; v.f = f;
    return (u16)((v.u + 0x7FFFu + ((v.u >> 16) & 1u)) >> 16);
}
__device__ __forceinline__ float bf2f(u16 h) {
    union { unsigned u; float f; } v; v.u = ((unsigned)h) << 16;
    return v.f;
}
// OCP e4m3fn quantize (RNE, saturating)
__device__ __forceinline__ u8 f2q(float f) {
    __hip_fp8_e4m3 t(f);
    return (u8)t.__x;
}
__device__ __forceinline__ long ld8(const u8* p) { return *(const long*)p; }

__device__ __forceinline__ float splusf(float x) {
    return fmaxf(x, 0.f) + __logf(1.f + __expf(-fabsf(x)));
}
// inverse of the channel permutation rho (sorts channels by (c%63, c)).
__device__ __forceinline__ int invperm(int k) {
    int m, q;
    if (k < 20) { m = k / 5; q = k - 5 * m; }
    else        { m = (k - 4) >> 2; q = (k - 4) & 3; }
    return m + 63 * q;
}

#define MID_ACT_P 272
#define WSCALE 64.f
#define WINV (1.f / 64.f)

// ---------------------------------------------------------------------------
// setup: masked fp8 weights (x64), hidden space relabeled by rho.
// W1: [l][wv][frag6(of 8)][lane][8]; frag=ks*2+f, f=0 -> rank-block wv,
//     f=1 -> rank-block 15-wv (wave owns blocks {wv, 15-wv}).
// WB: [l][bi][wv][frag9][lane][8]; frag<kA -> block wv slice frag,
//     else block 15-wv slice frag-kA, kA=(wv+2)>>1 (triangular banding,
//     9 frags/wave uniformly vs 16 -> 56% of work).
// WO: [l][y32][ks8][frag6][lane][8] (K-prefix banded; R16-proven).
// ---------------------------------------------------------------------------
__global__ __launch_bounds__(256) void setup_w(
    const float* __restrict__ Win, const float* __restrict__ bin,
    const float* __restrict__ Wctx, const float* __restrict__ bctx,
    const float* __restrict__ Wblk, const float* __restrict__ Wout,
    const float* __restrict__ bout, const float* __restrict__ eta,
    u8* __restrict__ W1, float* __restrict__ B1, u8* __restrict__ WB,
    u8* __restrict__ WO, float* __restrict__ BO, u8* __restrict__ AXE)
{
    const long N1 = 8L * 8 * 8 * 64 * 8;         // W1
    const long N2 = 8L * 256;
    const long N3 = 8L * 4 * 8 * 9 * 64 * 8;     // WB (banded, 9 frags)
    const long N4 = 8L * 32 * 8 * 6 * 64 * 8;    // WO
    const long N5 = 8L * 3072;
    const long N6 = 8192L * 32;
    const long tot = N1 + N2 + N3 + N4 + N5 + N6;
    for (long i = (long)blockIdx.x * blockDim.x + threadIdx.x; i < tot;
         i += (long)gridDim.x * blockDim.x) {
        long t = i;
        if (t < N1) {
            int off = (int)(t & 7), lane = (int)((t >> 3) & 63);
            int frag = (int)((t >> 9) & 7), wv = (int)((t >> 12) & 7);
            long l = t >> 15;
            int ks = frag >> 1, f = frag & 1;
            int pblk = f ? (15 - wv) : wv;
            int prow = pblk * 16 + (lane & 15);
            int row = invperm(prow);
            int c = ks * 32 + ((lane >> 4) << 3) + off;
            float v = 0.f;
            if (c < 64)      v = Win[(l * 256 + row) * 64 + c] * (((row % 63) >= c) ? 1.f : 0.f);
            else if (c < 96) v = Wctx[(l * 256 + row) * 32 + (c - 64)];
            W1[t] = f2q(v * WSCALE);
        } else if ((t -= N1) < N2) {
            long l = t >> 8; int k = (int)(t & 255);
            int c = invperm(k);
            B1[t] = bin[l * 256 + c] + bctx[l * 256 + c];
        } else if ((t -= N2) < N3) {
            int off = (int)(t & 7), lane = (int)((t >> 3) & 63);
            long r5 = t >> 9;                 // frag + 9*(wv + 8*(bi + 4*l))
            int frag = (int)(r5 % 9); long r6 = r5 / 9;
            int wv = (int)(r6 & 7);
            int bi = (int)((r6 >> 3) & 3);
            long l = r6 >> 5;
            int kA = (wv + 2) >> 1;
            int pblk, ksl;
            if (frag < kA) { pblk = wv;      ksl = frag; }
            else           { pblk = 15 - wv; ksl = frag - kA; }
            int prow = pblk * 16 + (lane & 15);
            int pc   = ksl * 32 + ((lane >> 4) << 3) + off;
            int row = invperm(prow), c = invperm(pc);
            float v = Wblk[(((size_t)l * 4 + bi) * 256 + row) * 256 + c] *
                      (((row % 63) >= (c % 63)) ? 1.f : 0.f);
            WB[t] = f2q(v * WSCALE);
        } else if ((t -= N3) < N4) {
            long l = t / 786432; int rem = (int)(t % 786432);
            int y = rem / 24576, r2 = rem % 24576;
            int ks = r2 / 3072, r3 = r2 % 3072;
            int frag = r3 / 512, r4 = r3 % 512;
            int lane = r4 / 8, off = r4 % 8;
            int op = y * 96 + frag * 16 + (lane & 15);
            int pj = ks * 32 + ((lane >> 4) << 3) + off;
            int j = invperm(pj);
            int fd = op / 48, mm = op % 48;
            float v = 0.f;
            if (mm < 47 && fd > (j % 63))
                v = Wout[((size_t)l * 3008 + fd * 47 + mm) * 256 + j];
            WO[t] = f2q(v * WSCALE);
        } else if ((t -= N4) < N5) {
            long l = t / 3072; int op = (int)(t % 3072);
            int fd = op / 48, mm = op % 48;
            BO[t] = (mm < 47) ? bout[l * 3008 + (long)fd * 47 + mm] : 0.f;
        } else {
            t -= N5;
            long b = t / 32; int p = (int)(t % 32);
            AXE[b * 96 + 64 + p] = f2q(eta[t]);
        }
    }
}

// permuted copy of bblk
__global__ __launch_bounds__(256) void perm_bias(
    const float* __restrict__ bblk, float* __restrict__ BBp)
{
    int t = blockIdx.x * 256 + threadIdx.x;   // 8*4*256 = 8192
    int k = t & 255;
    BBp[t] = bblk[(t & ~255) | invperm(k)];
}

// ---------------------------------------------------------------------------
// data stats
// ---------------------------------------------------------------------------
__global__ __launch_bounds__(128) void dstat(const float* __restrict__ D,
                                             float* __restrict__ DM)
{
    int j = threadIdx.x;
    float s = 0.f, q = 0.f;
    if (j < 65) {
        for (int m = 0; m < 256; ++m) {
            float v = D[m * 65 + j];
            s += v; q += v * v;
        }
        DM[j] = s * (1.f / 256.f);
    }
    __shared__ float red[128];
    red[j] = q; __syncthreads();
    for (int st = 64; st > 0; st >>= 1) {
        if (j < st) red[j] += red[j + st];
        __syncthreads();
    }
    if (j == 0) DM[65] = red[0] * (1.f / 256.f);
}

// ---------------------------------------------------------------------------
// prep0: flip z -> XF (f32) + AXE cols 0..63 (fp8)
// ---------------------------------------------------------------------------
__global__ __launch_bounds__(256) void prep0(
    const float* __restrict__ z, float* __restrict__ XF, u8* __restrict__ AXE)
{
    size_t gt = (size_t)blockIdx.x * 256 + threadIdx.x;
    size_t b = gt >> 6; int f = (int)(gt & 63);
    float v = z[b * 64 + (63 - f)];
    XF[gt] = v;
    AXE[b * 96 + f] = f2q(v);
}

// ---------------------------------------------------------------------------
// banded WB stage: 9 frags = kA for block wv (T0) + (9-kA) for block 15-wv
// (T1); compile-time KA via template (static indexing, uniform per wave).
// ---------------------------------------------------------------------------
template<int KA>
__device__ __forceinline__ void wb_stage(
    const u8* __restrict__ gW, const u8* __restrict__ act,
    int lane, int fr, int kg, f32x4& T0, f32x4& T1)
{
    constexpr int KB = 9 - KA;
    long wf[9];
#pragma unroll
    for (int j = 0; j < 9; ++j)
        wf[j] = ld8(gW + (j * 64 + lane) * 8);
#pragma unroll
    for (int j = 0; j < KA; ++j) {
        long af = ld8(&act[fr * MID_ACT_P + j * 32 + kg * 8]);
        T0 = __builtin_amdgcn_mfma_f32_16x16x32_fp8_fp8(wf[j], af, T0, 0, 0, 0);
    }
#pragma unroll
    for (int j = 0; j < KB; ++j) {
        long af = ld8(&act[fr * MID_ACT_P + j * 32 + kg * 8]);
        T1 = __builtin_amdgcn_mfma_f32_16x16x32_fp8_fp8(wf[KA + j], af, T1, 0, 0, 0);
    }
}

// fused_mid: all 5 mid GEMMs, fp8, triangular-banded WB stages.
// Wave wv owns rank-blocks {wv, 15-wv}; uniform 9 frags/wave on WB stages.
__global__ __launch_bounds__(512) void fused_mid(
    const u8* __restrict__ AXE, const u8* __restrict__ W1l,
    const float* __restrict__ B1l, const u8* __restrict__ WBl,
    const float* __restrict__ bbl, u8* __restrict__ HB)
{
    __shared__ u8 act[16 * MID_ACT_P];   // 4352 B
    const int tid = threadIdx.x;
    const int lane = tid & 63;
    const int wv = tid >> 6;
    const int fr = lane & 15, kg = lane >> 4;
    const int b0 = blockIdx.x * 16;
    const int cbA = wv * 16 + kg * 4;
    const int cbB = (15 - wv) * 16 + kg * 4;

    // stage-0 activations: AXE rows b0..b0+15 (96 u8 each = 6 int4)
    if (tid < 96) {
        int row = tid / 6, part = tid - row * 6;
        *(int4*)&act[row * MID_ACT_P + part * 16] =
            *(const int4*)&AXE[(size_t)(b0 + row) * 96 + part * 16];
    }

    f32x4 H0, H1, T0, T1;

    auto zeroT = [&]() {
        T0 = (f32x4){0.f, 0.f, 0.f, 0.f};
        T1 = (f32x4){0.f, 0.f, 0.f, 0.f};
    };
    // per-block epilogue helper
    auto epi1 = [&](f32x4& T, f32x4& H, int cb, const float* bias, int mode) {
        const float4 bs = *(const float4*)&bias[cb];
        f32x4 v = T;
        v[0] = v[0] * WINV + bs.x; v[1] = v[1] * WINV + bs.y;
        v[2] = v[2] * WINV + bs.z; v[3] = v[3] * WINV + bs.w;
        if (mode == 0) H = v;
        if (mode == 2 || mode == 3) {
            H[0] += v[0]; H[1] += v[1]; H[2] += v[2]; H[3] += v[3];
            v = H;
        }
        unsigned pk;
        if (mode != 3) {
            pk = (unsigned)f2q(fmaxf(v[0], 0.f))
               | ((unsigned)f2q(fmaxf(v[1], 0.f)) << 8)
               | ((unsigned)f2q(fmaxf(v[2], 0.f)) << 16)
               | ((unsigned)f2q(fmaxf(v[3], 0.f)) << 24);
            *(unsigned*)&act[fr * MID_ACT_P + cb] = pk;
        } else {
            pk = (unsigned)f2q(v[0]) | ((unsigned)f2q(v[1]) << 8)
               | ((unsigned)f2q(v[2]) << 16) | ((unsigned)f2q(v[3]) << 24);
            const int b = b0 + fr;
            const size_t idx =
                (((((size_t)(b >> 7) * 8 + (cb >> 5)) * 8 + ((b >> 4) & 7)) * 64)
                 + (((cb >> 3) & 3) * 16 + (b & 15))) * 8 + (cb & 7);
            *(unsigned*)&HB[idx] = pk;
        }
    };
    auto epi = [&](const float* bias, int mode) {
        epi1(T0, H0, cbA, bias, mode);
        epi1(T1, H1, cbB, bias, mode);
    };
    auto wbrun = [&](const u8* gW) {
        switch (wv >> 1) {
        case 0: wb_stage<1>(gW, act, lane, fr, kg, T0, T1); break;
        case 1: wb_stage<2>(gW, act, lane, fr, kg, T0, T1); break;
        case 2: wb_stage<3>(gW, act, lane, fr, kg, T0, T1); break;
        default: wb_stage<4>(gW, act, lane, fr, kg, T0, T1); break;
        }
    };

    // ---- stage 0: W1 (6 frags, both blocks full K=96) ----
    zeroT();
    {
        const u8* gW = W1l + wv * 4096;
        long wf[6];
#pragma unroll
        for (int j = 0; j < 6; ++j)
            wf[j] = ld8(gW + (j * 64 + lane) * 8);
        __syncthreads();                   // act0 visible
#pragma unroll
        for (int ks = 0; ks < 3; ++ks) {
            long af = ld8(&act[fr * MID_ACT_P + ks * 32 + kg * 8]);
            T0 = __builtin_amdgcn_mfma_f32_16x16x32_fp8_fp8(wf[ks * 2 + 0], af, T0, 0, 0, 0);
            T1 = __builtin_amdgcn_mfma_f32_16x16x32_fp8_fp8(wf[ks * 2 + 1], af, T1, 0, 0, 0);
        }
    }
    __syncthreads();
    epi(B1l, 0);
    // ---- 4 banded WB stages ----
    zeroT();
    __syncthreads();
    wbrun(WBl + 0 * 36864 + wv * 4608);
    __syncthreads();
    epi(bbl, 1);
    zeroT();
    __syncthreads();
    wbrun(WBl + 1 * 36864 + wv * 4608);
    __syncthreads();
    epi(bbl + 256, 2);
    zeroT();
    __syncthreads();
    wbrun(WBl + 2 * 36864 + wv * 4608);
    __syncthreads();
    epi(bbl + 2 * 256, 1);
    zeroT();
    __syncthreads();
    wbrun(WBl + 3 * 36864 + wv * 4608);
    __syncthreads();
    epi(bbl + 3 * 256, 3);
}

// ---------------------------------------------------------------------------
// Out-GEMM (128x96 tile, fp8) + fused RQS spline. K-banded (nk=(by+4)>>2),
// long blocks first. gl16 frag staging, dbuf. (R16-proven, unchanged.)
// ---------------------------------------------------------------------------
__global__ __launch_bounds__(256) void gemm_out_spline(
    const u8* __restrict__ A, const u8* __restrict__ Wo,
    const float* __restrict__ bo, const float* __restrict__ XF,
    float* __restrict__ Xn, float* __restrict__ XFnext, u8* __restrict__ AXE,
    float* __restrict__ LDP, int first)
{
    __shared__ u16 SM16[13312];          // 26624 B; staging aliases first 14336
    u8* SM8 = (u8*)SM16;
    const int tid = threadIdx.x;
    const int lane = tid & 63, wv = tid >> 6;
    const int wm = wv >> 1, wn = wv & 1;
    const int fr = lane & 15, kg = lane >> 4;
    const int by = 31 - (int)blockIdx.y;       // long blocks first
    const int m0 = blockIdx.x * 128, n0 = by * 96;
    const int nk = (by + 4) >> 2;              // 1..8 K-slices

    u8* Ab = SM8;                    // 2 x 4096 u8
    u8* Bb = SM8 + 8192;             // 2 x 3072 u8

    const u8* gA = A  + (size_t)blockIdx.x * 16384;   // [ks8][frag8][lane][8]
    const u8* gB = Wo + (size_t)by * 24576;           // [ks8][frag6][lane][8]

    f32x4 acc[4][3];
#pragma unroll
    for (int m = 0; m < 4; ++m)
#pragma unroll
        for (int n = 0; n < 3; ++n) acc[m][n] = (f32x4){0.f, 0.f, 0.f, 0.f};

    // prologue: slice 0 -> buf0 (linear gl16 copies)
    gl16(gA + tid * 16, Ab + tid * 16);
    if (tid < 192) gl16(gB + tid * 16, Bb + tid * 16);

    for (int ks = 0; ks < nk; ++ks) {
        __syncthreads();   // drains buf[ks&1] gl16; orders buffer reuse
        if (ks + 1 < nk) {
            const u8* sa = gA + (ks + 1) * 4096;
            const u8* sb = gB + (ks + 1) * 3072;
            u8* na = Ab + ((ks + 1) & 1) * 4096;
            u8* nb = Bb + ((ks + 1) & 1) * 3072;
            gl16(sa + tid * 16, na + tid * 16);
            if (tid < 192) gl16(sb + tid * 16, nb + tid * 16);
        }
        const u8* cA = Ab + (ks & 1) * 4096;
        const u8* cB = Bb + (ks & 1) * 3072;
        long af[4], bf[3];
#pragma unroll
        for (int m = 0; m < 4; ++m)
            af[m] = ld8(&cA[(wm * 4 + m) * 512 + lane * 8]);
#pragma unroll
        for (int n = 0; n < 3; ++n)
            bf[n] = ld8(&cB[(wn * 3 + n) * 512 + lane * 8]);
#pragma unroll
        for (int m = 0; m < 4; ++m)
#pragma unroll
            for (int n = 0; n < 3; ++n)
                acc[m][n] = __builtin_amdgcn_mfma_f32_16x16x32_fp8_fp8(bf[n], af[m], acc[m][n], 0, 0, 0);
    }
    __syncthreads();   // all frag reads done before dump aliases the buffers

    // dump acc/64 (+bias) as bf16, pitch 104 u16
#pragma unroll
    for (int m = 0; m < 4; ++m) {
        const int row = wm * 64 + m * 16 + fr;
#pragma unroll
        for (int n = 0; n < 3; ++n) {
            const int c0 = wn * 48 + n * 16 + kg * 4;
            const float4 bs = *(const float4*)&bo[n0 + c0];
            short4 q;
            q.x = (short)f2bf(acc[m][n][0] * WINV + bs.x);
            q.y = (short)f2bf(acc[m][n][1] * WINV + bs.y);
            q.z = (short)f2bf(acc[m][n][2] * WINV + bs.z);
            q.w = (short)f2bf(acc[m][n][3] * WINV + bs.w);
            *(short4*)&SM16[row * 104 + c0] = q;
        }
    }
    __syncthreads();

    // ---- RQS spline: one thread per (row, feature); 256 = 128 x 2 ----
    typedef short bf16x8 __attribute__((ext_vector_type(8)));
    const int r = tid >> 1, fi = tid & 1;
    const int b = m0 + r;
    const int fg = by * 2 + fi;
    const u16* o_ = &SM16[r * 104 + fi * 48];
    bf16x8 v0 = *(const bf16x8*)(o_);
    bf16x8 v1 = *(const bf16x8*)(o_ + 8);
    bf16x8 v2 = *(const bf16x8*)(o_ + 16);
    bf16x8 v3 = *(const bf16x8*)(o_ + 24);
    bf16x8 v4 = *(const bf16x8*)(o_ + 32);
    bf16x8 v5 = *(const bf16x8*)(o_ + 40);

    float xin = XF[(size_t)b * 64 + fg];
    bool inside = (xin >= -10.f) && (xin <= 10.f);
    float xs = fminf(fmaxf(xin, -10.f), 10.f);

    float ew[16], eh[16], ud[15];
#pragma unroll
    for (int i = 0; i < 8; ++i) {
        ew[i]     = bf2f((u16)v0[i]) * 0.0625f;
        ew[8 + i] = bf2f((u16)v1[i]) * 0.0625f;
        eh[i]     = bf2f((u16)v2[i]) * 0.0625f;
        eh[8 + i] = bf2f((u16)v3[i]) * 0.0625f;
    }
#pragma unroll
    for (int i = 0; i < 8; ++i) ud[i] = bf2f((u16)v4[i]);
#pragma unroll
    for (int i = 0; i < 7; ++i) ud[8 + i] = bf2f((u16)v5[i]);

    float mw = ew[0], mh = eh[0];
#pragma unroll
    for (int i = 1; i < 16; ++i) { mw = fmaxf(mw, ew[i]); mh = fmaxf(mh, eh[i]); }
    float sw = 0.f, sh = 0.f;
#pragma unroll
    for (int i = 0; i < 16; ++i) {
        ew[i] = __expf(ew[i] - mw); sw += ew[i];
        eh[i] = __expf(eh[i] - mh); sh += eh[i];
    }
    const float kw = 20.f * (1.f - 1.6e-7f) / sw;
    const float kh = 20.f * (1.f - 1.6e-7f) / sh;

    float cwk = -10.f, chk = -10.f;
    float icw = -10.f, ich = -10.f, iw = 1.f, ih = 1.f, udl = 0.f, udr = 0.f;
    int selk = 0;
#pragma unroll
    for (int k = 0; k < 16; ++k) {
        const float cw1 = (k == 15) ? 10.f : cwk + (2e-7f + kw * ew[k]);
        const float ch1 = (k == 15) ? 10.f : chk + (2e-7f + kh * eh[k]);
        if (xs >= cwk) {
            selk = k;
            icw = cwk; iw = cw1 - cwk;
            ich = chk; ih = ch1 - chk;
            udl = (k >= 1)  ? ud[k - 1] : 0.f;
            udr = (k <= 14) ? ud[k]     : 0.f;
        }
        cwk = cw1; chk = ch1;
    }
    float d0 = (selk == 0)  ? 1.f : 1e-8f + splusf(udl);
    float d1 = (selk == 15) ? 1.f : 1e-8f + splusf(udr);
    float delta = ih / iw;
    float t = (xs - icw) / iw;
    float tt = t * (1.f - t);
    float denom = delta + (d0 + d1 - 2.f * delta) * tt;
    float y = ich + ih * (delta * t * t + d0 * tt) / denom;
    float omt = 1.f - t;
    float dnum = delta * delta * (d1 * t * t + 2.f * delta * tt + d0 * omt * omt);
    float ldv = __logf(dnum) - 2.f * __logf(denom);
    if (!inside) { y = xin; ldv = 0.f; }

    Xn[(size_t)b * 64 + fg] = y;
    XFnext[(size_t)b * 64 + (63 - fg)] = y;
    AXE[(size_t)b * 96 + (63 - fg)] = f2q(y);

    float other = __shfl_xor(ldv, 1);
    if (fi == 0) {
        size_t o = (size_t)b * 32 + by;
        float v = ldv + other;
        LDP[o] = first ? v : (LDP[o] + v);
    }
}

// ---------------------------------------------------------------------------
// finals: stick-breaking + per-sample objective, then reduction
// ---------------------------------------------------------------------------
__global__ __launch_bounds__(256) void final1(
    const float* __restrict__ X, const float* __restrict__ z,
    const float* __restrict__ LDP, const float* __restrict__ DM,
    float* __restrict__ PART)
{
    int tid = threadIdx.x;
    int b = blockIdx.x * 256 + tid;
    float ldt = 0.f;
    for (int g = 0; g < 32; ++g) ldt += LDP[(size_t)b * 32 + g];
    float pre = 0.f, lvs = 0.f, wls = 0.f, lp = 0.f, tdm = 0.f, tsq = 0.f;
    const float LCLIP = -23.02585093f;
    for (int i = 0; i < 64; ++i) {
        float xi = X[(size_t)b * 64 + i];
        float lv = -splusf(-xi), l1 = -splusf(xi);
        float lt = lv + pre;
        float th = __expf(lt);
        lp += fmaxf(lt, LCLIP);
        tdm += th * DM[i]; tsq += th * th;
        lvs += lv; wls += (float)(64 - i) * l1;
        pre += l1;
    }
    float th = __expf(pre);
    lp += fmaxf(pre, LCLIP); tdm += th * DM[64]; tsq += th * th;
    float zs = 0.f;
    for (int i = 0; i < 64; ++i) { float zz = z[(size_t)b * 64 + i]; zs += zz * zz; }
    float logqz = -0.5f * zs - 58.812066f;
    float log_q = logqz - (ldt + lvs + wls);
    float log_lik = -0.5f * (DM[65] - 2.f * tdm + tsq);
    float val = log_q - lp - log_lik;

    __shared__ float red[256];
    red[tid] = val; __syncthreads();
    for (int s = 128; s > 0; s >>= 1) {
        if (tid < s) red[tid] += red[tid + s];
        __syncthreads();
    }
    if (tid == 0) PART[blockIdx.x] = red[0];
}

__global__ __launch_bounds__(64) void final2(const float* __restrict__ PART,
                                             float* __restrict__ out)
{
    int tid = threadIdx.x;
    float s = (tid < 32) ? PART[tid] : 0.f;
    for (int o = 16; o > 0; o >>= 1) s += __shfl_down(s, o);
    if (tid == 0) out[0] = s * (1.f / 8192.f);
}

// ---------------------------------------------------------------------------
extern "C" void kernel_launch(void* const* d_in, const int* in_sizes, int n_in,
                              void* d_out, int out_size, void* d_ws, size_t ws_size,
                              hipStream_t stream)
{
    (void)in_sizes; (void)n_in; (void)out_size; (void)ws_size;
    const float* z    = (const float*)d_in[0];
    const float* eta  = (const float*)d_in[1];
    const float* dat  = (const float*)d_in[2];
    const float* Win  = (const float*)d_in[3];
    const float* bin  = (const float*)d_in[4];
    const float* Wctx = (const float*)d_in[5];
    const float* bctx = (const float*)d_in[6];
    const float* Wblk = (const float*)d_in[7];
    const float* bblk = (const float*)d_in[8];
    const float* Wout = (const float*)d_in[9];
    const float* bout = (const float*)d_in[10];
    float* out = (float*)d_out;

    char* w = (char*)d_ws;
    size_t off = 0;
    auto alloc = [&](size_t bytes) {
        void* p = w + off;
        off += (bytes + 255) & ~(size_t)255;
        return p;
    };
    u8*    W1  = (u8*)   alloc(8L * 32768);
    float* B1  = (float*)alloc(8L * 256 * 4);
    u8*    WB  = (u8*)   alloc(8L * 147456);        // banded: 9 frags/wave
    float* BBp = (float*)alloc(8L * 4 * 256 * 4);
    u8*    WO  = (u8*)   alloc(8L * 786432);
    float* BO  = (float*)alloc(8L * 3072 * 4);
    u8*    AXE = (u8*)   alloc(8192L * 96);
    float* XFa = (float*)alloc(8192L * 64 * 4);
    float* XFb = (float*)alloc(8192L * 64 * 4);
    float* XC  = (float*)alloc(8192L * 64 * 4);
    u8*    HB  = (u8*)   alloc(8192L * 256);
    float* LDP = (float*)alloc(8192L * 32 * 4);
    float* DM  = (float*)alloc(66 * 4);
    float* PART= (float*)alloc(64 * 4);

    setup_w<<<dim3(2048), dim3(256), 0, stream>>>(
        Win, bin, Wctx, bctx, Wblk, Wout, bout, eta,
        W1, B1, WB, WO, BO, AXE);
    perm_bias<<<dim3(32), dim3(256), 0, stream>>>(bblk, BBp);
    dstat<<<dim3(1), dim3(128), 0, stream>>>(dat, DM);
    prep0<<<dim3(2048), dim3(256), 0, stream>>>(z, XFa, AXE);

    for (int l = 0; l < 8; ++l) {
        float* XFin  = (l & 1) ? XFb : XFa;
        float* XFout = (l & 1) ? XFa : XFb;
        fused_mid<<<dim3(512), dim3(512), 0, stream>>>(
            AXE, W1 + (size_t)l * 32768, B1 + l * 256,
            WB + (size_t)l * 147456, BBp + (size_t)l * 4 * 256, HB);
        gemm_out_spline<<<dim3(64, 32), dim3(256), 0, stream>>>(
            HB, WO + (size_t)l * 786432, BO + l * 3072, XFin,
            XC, XFout, AXE, LDP, (l == 0) ? 1 : 0);
    }
    final1<<<dim3(32), dim3(256), 0, stream>>>(XC, z, LDP, DM, PART);
    final2<<<dim3(1), dim3(64), 0, stream>>>(PART, out);
}

// Round 19
// 282.031 us; speedup vs baseline: 1.1299x; 1.0144x over previous
//
#include <hip/hip_runtime.h>
#include <hip/hip_fp8.h>
#include <math.h>

typedef float f32x4 __attribute__((ext_vector_type(4)));
typedef unsigned short u16;
typedef unsigned char u8;

typedef const __attribute__((address_space(1))) unsigned int ga_u32;
typedef __attribute__((address_space(3))) unsigned int ls_u32;

__device__ __forceinline__ void gl16(const void* g, void* l) {
    __builtin_amdgcn_global_load_lds((ga_u32*)g, (ls_u32*)l, 16, 0, 0);
}

__device__ __forceinline__ u16 f2bf(float f) {
    union { float f; unsigned u; } v; v.f = f;
    return (u16)((v.u + 0x7FFFu + ((v.u >> 16) & 1u)) >> 16);
}
__device__ __forceinline__ float bf2f(u16 h) {
    union { unsigned u; float f; } v; v.u = ((unsigned)h) << 16;
    return v.f;
}
// OCP e4m3fn quantize (RNE, saturating)
__device__ __forceinline__ u8 f2q(float f) {
    __hip_fp8_e4m3 t(f);
    return (u8)t.__x;
}
__device__ __forceinline__ long ld8(const u8* p) { return *(const long*)p; }

__device__ __forceinline__ float splusf(float x) {
    return fmaxf(x, 0.f) + __logf(1.f + __expf(-fabsf(x)));
}
// inverse of the channel permutation rho (sorts channels by (c%63, c)).
__device__ __forceinline__ int invperm(int k) {
    int m, q;
    if (k < 20) { m = k / 5; q = k - 5 * m; }
    else        { m = (k - 4) >> 2; q = (k - 4) & 3; }
    return m + 63 * q;
}

#define MID_ACT_P 272
#define WSCALE 64.f
#define WINV (1.f / 64.f)

// ---------------------------------------------------------------------------
// setup: masked fp8 weights (x64), hidden space relabeled by rho; also does
// prep0 (z flip -> XF + AXE) and the bblk permutation (fewer dispatches).
// W1: [l][wv][frag6(of 8)][lane][8]; f=0 -> rank-block wv, f=1 -> 15-wv.
// WB: [l][bi][wv][frag9][lane][8]; triangular banding, 9 frags/wave.
// WO: [l][y32][ks8][frag6][lane][8]; K-prefix banded.
// ---------------------------------------------------------------------------
__global__ __launch_bounds__(256) void setup_w(
    const float* __restrict__ Win, const float* __restrict__ bin,
    const float* __restrict__ Wctx, const float* __restrict__ bctx,
    const float* __restrict__ Wblk, const float* __restrict__ Wout,
    const float* __restrict__ bout, const float* __restrict__ eta,
    const float* __restrict__ z, const float* __restrict__ bblk,
    u8* __restrict__ W1, float* __restrict__ B1, u8* __restrict__ WB,
    u8* __restrict__ WO, float* __restrict__ BO, u8* __restrict__ AXE,
    float* __restrict__ XF, float* __restrict__ BBp)
{
    const long N1 = 8L * 8 * 8 * 64 * 8;         // W1
    const long N2 = 8L * 256;
    const long N3 = 8L * 4 * 8 * 9 * 64 * 8;     // WB (banded, 9 frags)
    const long N4 = 8L * 32 * 8 * 6 * 64 * 8;    // WO
    const long N5 = 8L * 3072;
    const long N6 = 8192L * 32;                  // eta -> AXE
    const long N7 = 8192L * 64;                  // prep0: z -> XF + AXE
    const long N8 = 8L * 4 * 256;                // perm bblk
    const long tot = N1 + N2 + N3 + N4 + N5 + N6 + N7 + N8;
    for (long i = (long)blockIdx.x * blockDim.x + threadIdx.x; i < tot;
         i += (long)gridDim.x * blockDim.x) {
        long t = i;
        if (t < N1) {
            int off = (int)(t & 7), lane = (int)((t >> 3) & 63);
            int frag = (int)((t >> 9) & 7), wv = (int)((t >> 12) & 7);
            long l = t >> 15;
            int ks = frag >> 1, f = frag & 1;
            int pblk = f ? (15 - wv) : wv;
            int prow = pblk * 16 + (lane & 15);
            int row = invperm(prow);
            int c = ks * 32 + ((lane >> 4) << 3) + off;
            float v = 0.f;
            if (c < 64)      v = Win[(l * 256 + row) * 64 + c] * (((row % 63) >= c) ? 1.f : 0.f);
            else if (c < 96) v = Wctx[(l * 256 + row) * 32 + (c - 64)];
            W1[t] = f2q(v * WSCALE);
        } else if ((t -= N1) < N2) {
            long l = t >> 8; int k = (int)(t & 255);
            int c = invperm(k);
            B1[t] = bin[l * 256 + c] + bctx[l * 256 + c];
        } else if ((t -= N2) < N3) {
            int off = (int)(t & 7), lane = (int)((t >> 3) & 63);
            long r5 = t >> 9;
            int frag = (int)(r5 % 9); long r6 = r5 / 9;
            int wv = (int)(r6 & 7);
            int bi = (int)((r6 >> 3) & 3);
            long l = r6 >> 5;
            int kA = (wv + 2) >> 1;
            int pblk, ksl;
            if (frag < kA) { pblk = wv;      ksl = frag; }
            else           { pblk = 15 - wv; ksl = frag - kA; }
            int prow = pblk * 16 + (lane & 15);
            int pc   = ksl * 32 + ((lane >> 4) << 3) + off;
            int row = invperm(prow), c = invperm(pc);
            float v = Wblk[(((size_t)l * 4 + bi) * 256 + row) * 256 + c] *
                      (((row % 63) >= (c % 63)) ? 1.f : 0.f);
            WB[t] = f2q(v * WSCALE);
        } else if ((t -= N3) < N4) {
            long l = t / 786432; int rem = (int)(t % 786432);
            int y = rem / 24576, r2 = rem % 24576;
            int ks = r2 / 3072, r3 = r2 % 3072;
            int frag = r3 / 512, r4 = r3 % 512;
            int lane = r4 / 8, off = r4 % 8;
            int op = y * 96 + frag * 16 + (lane & 15);
            int pj = ks * 32 + ((lane >> 4) << 3) + off;
            int j = invperm(pj);
            int fd = op / 48, mm = op % 48;
            float v = 0.f;
            if (mm < 47 && fd > (j % 63))
                v = Wout[((size_t)l * 3008 + fd * 47 + mm) * 256 + j];
            WO[t] = f2q(v * WSCALE);
        } else if ((t -= N4) < N5) {
            long l = t / 3072; int op = (int)(t % 3072);
            int fd = op / 48, mm = op % 48;
            BO[t] = (mm < 47) ? bout[l * 3008 + (long)fd * 47 + mm] : 0.f;
        } else if ((t -= N5) < N6) {
            long b = t / 32; int p = (int)(t % 32);
            AXE[b * 96 + 64 + p] = f2q(eta[t]);
        } else if ((t -= N6) < N7) {
            long b = t >> 6; int f = (int)(t & 63);
            float v = z[b * 64 + (63 - f)];
            XF[t] = v;
            AXE[b * 96 + f] = f2q(v);
        } else {
            t -= N7;
            int k = (int)(t & 255);
            BBp[t] = bblk[(t & ~(long)255) | invperm(k)];
        }
    }
}

// ---------------------------------------------------------------------------
// data stats
// ---------------------------------------------------------------------------
__global__ __launch_bounds__(128) void dstat(const float* __restrict__ D,
                                             float* __restrict__ DM)
{
    int j = threadIdx.x;
    float s = 0.f, q = 0.f;
    if (j < 65) {
        for (int m = 0; m < 256; ++m) {
            float v = D[m * 65 + j];
            s += v; q += v * v;
        }
        DM[j] = s * (1.f / 256.f);
    }
    __shared__ float red[128];
    red[j] = q; __syncthreads();
    for (int st = 64; st > 0; st >>= 1) {
        if (j < st) red[j] += red[j + st];
        __syncthreads();
    }
    if (j == 0) DM[65] = red[0] * (1.f / 256.f);
}

// ---------------------------------------------------------------------------
// banded WB stage: 9 frags = kA for block wv (T0) + (9-kA) for block 15-wv
// (T1); compile-time KA (static indexing, uniform per wave).
// ---------------------------------------------------------------------------
template<int KA>
__device__ __forceinline__ void wb_stage(
    const u8* __restrict__ gW, const u8* __restrict__ act,
    int lane, int fr, int kg, f32x4& T0, f32x4& T1)
{
    constexpr int KB = 9 - KA;
    long wf[9];
#pragma unroll
    for (int j = 0; j < 9; ++j)
        wf[j] = ld8(gW + (j * 64 + lane) * 8);
#pragma unroll
    for (int j = 0; j < KA; ++j) {
        long af = ld8(&act[fr * MID_ACT_P + j * 32 + kg * 8]);
        T0 = __builtin_amdgcn_mfma_f32_16x16x32_fp8_fp8(wf[j], af, T0, 0, 0, 0);
    }
#pragma unroll
    for (int j = 0; j < KB; ++j) {
        long af = ld8(&act[fr * MID_ACT_P + j * 32 + kg * 8]);
        T1 = __builtin_amdgcn_mfma_f32_16x16x32_fp8_fp8(wf[KA + j], af, T1, 0, 0, 0);
    }
}

// fused_mid: all 5 mid GEMMs, fp8, triangular-banded WB, ACT DOUBLE-BUFFERED:
// stage s reads act[p], epilogue writes act[p^1] -> ONE barrier per stage
// boundary (5 total instead of 11).
__global__ __launch_bounds__(512) void fused_mid(
    const u8* __restrict__ AXE, const u8* __restrict__ W1l,
    const float* __restrict__ B1l, const u8* __restrict__ WBl,
    const float* __restrict__ bbl, u8* __restrict__ HB)
{
    __shared__ u8 act[2][16 * MID_ACT_P];   // 8704 B
    const int tid = threadIdx.x;
    const int lane = tid & 63;
    const int wv = tid >> 6;
    const int fr = lane & 15, kg = lane >> 4;
    const int b0 = blockIdx.x * 16;
    const int cbA = wv * 16 + kg * 4;
    const int cbB = (15 - wv) * 16 + kg * 4;

    // stage-0 activations: AXE rows b0..b0+15 -> act[0]
    if (tid < 96) {
        int row = tid / 6, part = tid - row * 6;
        *(int4*)&act[0][row * MID_ACT_P + part * 16] =
            *(const int4*)&AXE[(size_t)(b0 + row) * 96 + part * 16];
    }

    f32x4 H0, H1, T0, T1;

    auto zeroT = [&]() {
        T0 = (f32x4){0.f, 0.f, 0.f, 0.f};
        T1 = (f32x4){0.f, 0.f, 0.f, 0.f};
    };
    // per-block epilogue; writes fp8 act rows into actw (next buffer)
    auto epi1 = [&](f32x4& T, f32x4& H, int cb, const float* bias, int mode,
                    u8* actw) {
        const float4 bs = *(const float4*)&bias[cb];
        f32x4 v = T;
        v[0] = v[0] * WINV + bs.x; v[1] = v[1] * WINV + bs.y;
        v[2] = v[2] * WINV + bs.z; v[3] = v[3] * WINV + bs.w;
        if (mode == 0) H = v;
        if (mode == 2 || mode == 3) {
            H[0] += v[0]; H[1] += v[1]; H[2] += v[2]; H[3] += v[3];
            v = H;
        }
        unsigned pk;
        if (mode != 3) {
            pk = (unsigned)f2q(fmaxf(v[0], 0.f))
               | ((unsigned)f2q(fmaxf(v[1], 0.f)) << 8)
               | ((unsigned)f2q(fmaxf(v[2], 0.f)) << 16)
               | ((unsigned)f2q(fmaxf(v[3], 0.f)) << 24);
            *(unsigned*)&actw[fr * MID_ACT_P + cb] = pk;
        } else {
            pk = (unsigned)f2q(v[0]) | ((unsigned)f2q(v[1]) << 8)
               | ((unsigned)f2q(v[2]) << 16) | ((unsigned)f2q(v[3]) << 24);
            const int b = b0 + fr;
            const size_t idx =
                (((((size_t)(b >> 7) * 8 + (cb >> 5)) * 8 + ((b >> 4) & 7)) * 64)
                 + (((cb >> 3) & 3) * 16 + (b & 15))) * 8 + (cb & 7);
            *(unsigned*)&HB[idx] = pk;
        }
    };
    auto epi = [&](const float* bias, int mode, u8* actw) {
        epi1(T0, H0, cbA, bias, mode, actw);
        epi1(T1, H1, cbB, bias, mode, actw);
    };
    auto wbrun = [&](const u8* gW, const u8* actr) {
        switch (wv >> 1) {
        case 0: wb_stage<1>(gW, actr, lane, fr, kg, T0, T1); break;
        case 1: wb_stage<2>(gW, actr, lane, fr, kg, T0, T1); break;
        case 2: wb_stage<3>(gW, actr, lane, fr, kg, T0, T1); break;
        default: wb_stage<4>(gW, actr, lane, fr, kg, T0, T1); break;
        }
    };

    // ---- stage 0: W1 (6 frags, both blocks full K=96), reads act[0] ----
    zeroT();
    {
        const u8* gW = W1l + wv * 4096;
        long wf[6];
#pragma unroll
        for (int j = 0; j < 6; ++j)
            wf[j] = ld8(gW + (j * 64 + lane) * 8);
        __syncthreads();                   // act[0] staged
#pragma unroll
        for (int ks = 0; ks < 3; ++ks) {
            long af = ld8(&act[0][fr * MID_ACT_P + ks * 32 + kg * 8]);
            T0 = __builtin_amdgcn_mfma_f32_16x16x32_fp8_fp8(wf[ks * 2 + 0], af, T0, 0, 0, 0);
            T1 = __builtin_amdgcn_mfma_f32_16x16x32_fp8_fp8(wf[ks * 2 + 1], af, T1, 0, 0, 0);
        }
    }
    epi(B1l, 0, act[1]);                   // h0 -> act[1]
    zeroT();
    __syncthreads();
    wbrun(WBl + 0 * 36864 + wv * 4608, act[1]);
    epi(bbl, 1, act[0]);                   // t -> act[0]
    zeroT();
    __syncthreads();
    wbrun(WBl + 1 * 36864 + wv * 4608, act[0]);
    epi(bbl + 256, 2, act[1]);             // h1 -> act[1]
    zeroT();
    __syncthreads();
    wbrun(WBl + 2 * 36864 + wv * 4608, act[1]);
    epi(bbl + 2 * 256, 1, act[0]);         // t -> act[0]
    zeroT();
    __syncthreads();
    wbrun(WBl + 3 * 36864 + wv * 4608, act[0]);
    epi(bbl + 3 * 256, 3, (u8*)nullptr);   // h2 -> HB (global)
}

// ---------------------------------------------------------------------------
// Out-GEMM (128x96 tile, fp8) + fused RQS spline. K-banded (nk=(by+4)>>2),
// long blocks first. gl16 frag staging, dbuf. (R16-proven, unchanged.)
// ---------------------------------------------------------------------------
__global__ __launch_bounds__(256) void gemm_out_spline(
    const u8* __restrict__ A, const u8* __restrict__ Wo,
    const float* __restrict__ bo, const float* __restrict__ XF,
    float* __restrict__ Xn, float* __restrict__ XFnext, u8* __restrict__ AXE,
    float* __restrict__ LDP, int first)
{
    __shared__ u16 SM16[13312];          // 26624 B; staging aliases first 14336
    u8* SM8 = (u8*)SM16;
    const int tid = threadIdx.x;
    const int lane = tid & 63, wv = tid >> 6;
    const int wm = wv >> 1, wn = wv & 1;
    const int fr = lane & 15, kg = lane >> 4;
    const int by = 31 - (int)blockIdx.y;       // long blocks first
    const int m0 = blockIdx.x * 128, n0 = by * 96;
    const int nk = (by + 4) >> 2;              // 1..8 K-slices

    u8* Ab = SM8;                    // 2 x 4096 u8
    u8* Bb = SM8 + 8192;             // 2 x 3072 u8

    const u8* gA = A  + (size_t)blockIdx.x * 16384;   // [ks8][frag8][lane][8]
    const u8* gB = Wo + (size_t)by * 24576;           // [ks8][frag6][lane][8]

    f32x4 acc[4][3];
#pragma unroll
    for (int m = 0; m < 4; ++m)
#pragma unroll
        for (int n = 0; n < 3; ++n) acc[m][n] = (f32x4){0.f, 0.f, 0.f, 0.f};

    // prologue: slice 0 -> buf0 (linear gl16 copies)
    gl16(gA + tid * 16, Ab + tid * 16);
    if (tid < 192) gl16(gB + tid * 16, Bb + tid * 16);

    for (int ks = 0; ks < nk; ++ks) {
        __syncthreads();   // drains buf[ks&1] gl16; orders buffer reuse
        if (ks + 1 < nk) {
            const u8* sa = gA + (ks + 1) * 4096;
            const u8* sb = gB + (ks + 1) * 3072;
            u8* na = Ab + ((ks + 1) & 1) * 4096;
            u8* nb = Bb + ((ks + 1) & 1) * 3072;
            gl16(sa + tid * 16, na + tid * 16);
            if (tid < 192) gl16(sb + tid * 16, nb + tid * 16);
        }
        const u8* cA = Ab + (ks & 1) * 4096;
        const u8* cB = Bb + (ks & 1) * 3072;
        long af[4], bf[3];
#pragma unroll
        for (int m = 0; m < 4; ++m)
            af[m] = ld8(&cA[(wm * 4 + m) * 512 + lane * 8]);
#pragma unroll
        for (int n = 0; n < 3; ++n)
            bf[n] = ld8(&cB[(wn * 3 + n) * 512 + lane * 8]);
#pragma unroll
        for (int m = 0; m < 4; ++m)
#pragma unroll
            for (int n = 0; n < 3; ++n)
                acc[m][n] = __builtin_amdgcn_mfma_f32_16x16x32_fp8_fp8(bf[n], af[m], acc[m][n], 0, 0, 0);
    }
    __syncthreads();   // all frag reads done before dump aliases the buffers

    // dump acc/64 (+bias) as bf16, pitch 104 u16
#pragma unroll
    for (int m = 0; m < 4; ++m) {
        const int row = wm * 64 + m * 16 + fr;
#pragma unroll
        for (int n = 0; n < 3; ++n) {
            const int c0 = wn * 48 + n * 16 + kg * 4;
            const float4 bs = *(const float4*)&bo[n0 + c0];
            short4 q;
            q.x = (short)f2bf(acc[m][n][0] * WINV + bs.x);
            q.y = (short)f2bf(acc[m][n][1] * WINV + bs.y);
            q.z = (short)f2bf(acc[m][n][2] * WINV + bs.z);
            q.w = (short)f2bf(acc[m][n][3] * WINV + bs.w);
            *(short4*)&SM16[row * 104 + c0] = q;
        }
    }
    __syncthreads();

    // ---- RQS spline: one thread per (row, feature); 256 = 128 x 2 ----
    typedef short bf16x8 __attribute__((ext_vector_type(8)));
    const int r = tid >> 1, fi = tid & 1;
    const int b = m0 + r;
    const int fg = by * 2 + fi;
    const u16* o_ = &SM16[r * 104 + fi * 48];
    bf16x8 v0 = *(const bf16x8*)(o_);
    bf16x8 v1 = *(const bf16x8*)(o_ + 8);
    bf16x8 v2 = *(const bf16x8*)(o_ + 16);
    bf16x8 v3 = *(const bf16x8*)(o_ + 24);
    bf16x8 v4 = *(const bf16x8*)(o_ + 32);
    bf16x8 v5 = *(const bf16x8*)(o_ + 40);

    float xin = XF[(size_t)b * 64 + fg];
    bool inside = (xin >= -10.f) && (xin <= 10.f);
    float xs = fminf(fmaxf(xin, -10.f), 10.f);

    float ew[16], eh[16], ud[15];
#pragma unroll
    for (int i = 0; i < 8; ++i) {
        ew[i]     = bf2f((u16)v0[i]) * 0.0625f;
        ew[8 + i] = bf2f((u16)v1[i]) * 0.0625f;
        eh[i]     = bf2f((u16)v2[i]) * 0.0625f;
        eh[8 + i] = bf2f((u16)v3[i]) * 0.0625f;
    }
#pragma unroll
    for (int i = 0; i < 8; ++i) ud[i] = bf2f((u16)v4[i]);
#pragma unroll
    for (int i = 0; i < 7; ++i) ud[8 + i] = bf2f((u16)v5[i]);

    float mw = ew[0], mh = eh[0];
#pragma unroll
    for (int i = 1; i < 16; ++i) { mw = fmaxf(mw, ew[i]); mh = fmaxf(mh, eh[i]); }
    float sw = 0.f, sh = 0.f;
#pragma unroll
    for (int i = 0; i < 16; ++i) {
        ew[i] = __expf(ew[i] - mw); sw += ew[i];
        eh[i] = __expf(eh[i] - mh); sh += eh[i];
    }
    const float kw = 20.f * (1.f - 1.6e-7f) / sw;
    const float kh = 20.f * (1.f - 1.6e-7f) / sh;

    float cwk = -10.f, chk = -10.f;
    float icw = -10.f, ich = -10.f, iw = 1.f, ih = 1.f, udl = 0.f, udr = 0.f;
    int selk = 0;
#pragma unroll
    for (int k = 0; k < 16; ++k) {
        const float cw1 = (k == 15) ? 10.f : cwk + (2e-7f + kw * ew[k]);
        const float ch1 = (k == 15) ? 10.f : chk + (2e-7f + kh * eh[k]);
        if (xs >= cwk) {
            selk = k;
            icw = cwk; iw = cw1 - cwk;
            ich = chk; ih = ch1 - chk;
            udl = (k >= 1)  ? ud[k - 1] : 0.f;
            udr = (k <= 14) ? ud[k]     : 0.f;
        }
        cwk = cw1; chk = ch1;
    }
    float d0 = (selk == 0)  ? 1.f : 1e-8f + splusf(udl);
    float d1 = (selk == 15) ? 1.f : 1e-8f + splusf(udr);
    float delta = ih / iw;
    float t = (xs - icw) / iw;
    float tt = t * (1.f - t);
    float denom = delta + (d0 + d1 - 2.f * delta) * tt;
    float y = ich + ih * (delta * t * t + d0 * tt) / denom;
    float omt = 1.f - t;
    float dnum = delta * delta * (d1 * t * t + 2.f * delta * tt + d0 * omt * omt);
    float ldv = __logf(dnum) - 2.f * __logf(denom);
    if (!inside) { y = xin; ldv = 0.f; }

    Xn[(size_t)b * 64 + fg] = y;
    XFnext[(size_t)b * 64 + (63 - fg)] = y;
    AXE[(size_t)b * 96 + (63 - fg)] = f2q(y);

    float other = __shfl_xor(ldv, 1);
    if (fi == 0) {
        size_t o = (size_t)b * 32 + by;
        float v = ldv + other;
        LDP[o] = first ? v : (LDP[o] + v);
    }
}

// ---------------------------------------------------------------------------
// finals: stick-breaking + per-sample objective, then reduction
// ---------------------------------------------------------------------------
__global__ __launch_bounds__(256) void final1(
    const float* __restrict__ X, const float* __restrict__ z,
    const float* __restrict__ LDP, const float* __restrict__ DM,
    float* __restrict__ PART)
{
    int tid = threadIdx.x;
    int b = blockIdx.x * 256 + tid;
    float ldt = 0.f;
    for (int g = 0; g < 32; ++g) ldt += LDP[(size_t)b * 32 + g];
    float pre = 0.f, lvs = 0.f, wls = 0.f, lp = 0.f, tdm = 0.f, tsq = 0.f;
    const float LCLIP = -23.02585093f;
    for (int i = 0; i < 64; ++i) {
        float xi = X[(size_t)b * 64 + i];
        float lv = -splusf(-xi), l1 = -splusf(xi);
        float lt = lv + pre;
        float th = __expf(lt);
        lp += fmaxf(lt, LCLIP);
        tdm += th * DM[i]; tsq += th * th;
        lvs += lv; wls += (float)(64 - i) * l1;
        pre += l1;
    }
    float th = __expf(pre);
    lp += fmaxf(pre, LCLIP); tdm += th * DM[64]; tsq += th * th;
    float zs = 0.f;
    for (int i = 0; i < 64; ++i) { float zz = z[(size_t)b * 64 + i]; zs += zz * zz; }
    float logqz = -0.5f * zs - 58.812066f;
    float log_q = logqz - (ldt + lvs + wls);
    float log_lik = -0.5f * (DM[65] - 2.f * tdm + tsq);
    float val = log_q - lp - log_lik;

    __shared__ float red[256];
    red[tid] = val; __syncthreads();
    for (int s = 128; s > 0; s >>= 1) {
        if (tid < s) red[tid] += red[tid + s];
        __syncthreads();
    }
    if (tid == 0) PART[blockIdx.x] = red[0];
}

__global__ __launch_bounds__(64) void final2(const float* __restrict__ PART,
                                             float* __restrict__ out)
{
    int tid = threadIdx.x;
    float s = (tid < 32) ? PART[tid] : 0.f;
    for (int o = 16; o > 0; o >>= 1) s += __shfl_down(s, o);
    if (tid == 0) out[0] = s * (1.f / 8192.f);
}

// ---------------------------------------------------------------------------
extern "C" void kernel_launch(void* const* d_in, const int* in_sizes, int n_in,
                              void* d_out, int out_size, void* d_ws, size_t ws_size,
                              hipStream_t stream)
{
    (void)in_sizes; (void)n_in; (void)out_size; (void)ws_size;
    const float* z    = (const float*)d_in[0];
    const float* eta  = (const float*)d_in[1];
    const float* dat  = (const float*)d_in[2];
    const float* Win  = (const float*)d_in[3];
    const float* bin  = (const float*)d_in[4];
    const float* Wctx = (const float*)d_in[5];
    const float* bctx = (const float*)d_in[6];
    const float* Wblk = (const float*)d_in[7];
    const float* bblk = (const float*)d_in[8];
    const float* Wout = (const float*)d_in[9];
    const float* bout = (const float*)d_in[10];
    float* out = (float*)d_out;

    char* w = (char*)d_ws;
    size_t off = 0;
    auto alloc = [&](size_t bytes) {
        void* p = w + off;
        off += (bytes + 255) & ~(size_t)255;
        return p;
    };
    u8*    W1  = (u8*)   alloc(8L * 32768);
    float* B1  = (float*)alloc(8L * 256 * 4);
    u8*    WB  = (u8*)   alloc(8L * 147456);        // banded: 9 frags/wave
    float* BBp = (float*)alloc(8L * 4 * 256 * 4);
    u8*    WO  = (u8*)   alloc(8L * 786432);
    float* BO  = (float*)alloc(8L * 3072 * 4);
    u8*    AXE = (u8*)   alloc(8192L * 96);
    float* XFa = (float*)alloc(8192L * 64 * 4);
    float* XFb = (float*)alloc(8192L * 64 * 4);
    float* XC  = (float*)alloc(8192L * 64 * 4);
    u8*    HB  = (u8*)   alloc(8192L * 256);
    float* LDP = (float*)alloc(8192L * 32 * 4);
    float* DM  = (float*)alloc(66 * 4);
    float* PART= (float*)alloc(64 * 4);

    setup_w<<<dim3(2048), dim3(256), 0, stream>>>(
        Win, bin, Wctx, bctx, Wblk, Wout, bout, eta, z, bblk,
        W1, B1, WB, WO, BO, AXE, XFa, BBp);
    dstat<<<dim3(1), dim3(128), 0, stream>>>(dat, DM);

    for (int l = 0; l < 8; ++l) {
        float* XFin  = (l & 1) ? XFb : XFa;
        float* XFout = (l & 1) ? XFa : XFb;
        fused_mid<<<dim3(512), dim3(512), 0, stream>>>(
            AXE, W1 + (size_t)l * 32768, B1 + l * 256,
            WB + (size_t)l * 147456, BBp + (size_t)l * 4 * 256, HB);
        gemm_out_spline<<<dim3(64, 32), dim3(256), 0, stream>>>(
            HB, WO + (size_t)l * 786432, BO + l * 3072, XFin,
            XC, XFout, AXE, LDP, (l == 0) ? 1 : 0);
    }
    final1<<<dim3(32), dim3(256), 0, stream>>>(XC, z, LDP, DM, PART);
    final2<<<dim3(1), dim3(64), 0, stream>>>(PART, out);
}